// Round 3
// baseline (630.885 us; speedup 1.0000x reference)
//
#include <hip/hip_runtime.h>
#include <stdint.h>

// Sizes (fixed by the problem)
#define BATCH   65536
#define D_IN    784
#define KP      800      // D_IN padded to a multiple of BK=32
#define HDIM    512
#define D_OUT   10
#define NCODE   512

typedef _Float16 f16;
typedef _Float16 f16x8 __attribute__((ext_vector_type(8)));
typedef float    f32x4 __attribute__((ext_vector_type(4)));

__device__ __forceinline__ void gld_lds16(const void* g, void* l) {
  __builtin_amdgcn_global_load_lds((const __attribute__((address_space(1))) void*)g,
                                   (__attribute__((address_space(3))) void*)l, 16, 0, 0);
}

// ---------------- x: fp32 (65536,784) -> f16 (65536,800) zero-padded ----------------
__global__ void k_convert_x(const float* __restrict__ x, f16* __restrict__ xh) {
  int t = blockIdx.x * 256 + threadIdx.x;        // 65536*100 threads
  int r = t / 100;
  int c = (t - r * 100) * 8;
  f16x8 o;
  if (c < D_IN) {  // 784 % 8 == 0, so chunks are fully valid or fully pad
    const float4 a = *(const float4*)(x + (size_t)r * D_IN + c);
    const float4 b = *(const float4*)(x + (size_t)r * D_IN + c + 4);
    o[0]=(f16)a.x; o[1]=(f16)a.y; o[2]=(f16)a.z; o[3]=(f16)a.w;
    o[4]=(f16)b.x; o[5]=(f16)b.y; o[6]=(f16)b.z; o[7]=(f16)b.w;
  } else {
    #pragma unroll
    for (int j = 0; j < 8; ++j) o[j] = (f16)0.f;
  }
  *(f16x8*)(xh + (size_t)r * KP + c) = o;
}

// ---------------- VQ W1: blocks (og<128, ig<112), dim 28 ----------------
// Replicates numpy-fp32 semantics of the reference:
//   dist = fl(fl(s - 2*dot) + t)
//   s = pairwise-sum of fl(v*v) (numpy scalar 8-acc path, n=28)
//   dot = sequential ascending-k fp32 FMA chain (BLAS sgemm micro-kernel order)
//   t = sequential axis-0 sum of fl(e*e)
//   argmin: first index of minimum.
__global__ void k_vq1(const float* __restrict__ W1, const float* __restrict__ E1,
                      f16* __restrict__ qW1, float* __restrict__ diffacc) {
  #pragma clang fp contract(off)
  __shared__ float E1s[28 * NCODE];
  __shared__ float Ts[NCODE];
  for (int i = threadIdx.x; i < 28 * NCODE; i += 256) E1s[i] = E1[i];
  __syncthreads();
  for (int k = threadIdx.x; k < NCODE; k += 256) {
    float e0 = E1s[k];
    float t = e0 * e0;                 // fl(e^2)
    for (int j = 1; j < 28; ++j) {
      float e = E1s[j * NCODE + k];
      float ee = e * e;                // fl(e^2)
      t = t + ee;                      // sequential adds (numpy axis-0 reduce)
    }
    Ts[k] = t;
  }
  __syncthreads();
  const int wid = threadIdx.x >> 6, lane = threadIdx.x & 63;
  const int bid = blockIdx.x * 4 + wid;          // < 14336
  const int og = bid / 112, ig = bid % 112;
  float v[28], vv[28];
  #pragma unroll
  for (int j = 0; j < 28; ++j) {
    int om = j & 3, im = j >> 2;
    v[j] = W1[(og * 4 + om) * D_IN + ig * 7 + im];
    vv[j] = v[j] * v[j];
  }
  // numpy pairwise_sum, scalar path, n=28: r[j]=(a[j]+a[8+j])+a[16+j]; combine; tail 24..27
  float r[8];
  #pragma unroll
  for (int j = 0; j < 8; ++j) r[j] = vv[j];
  #pragma unroll
  for (int j = 0; j < 8; ++j) r[j] = r[j] + vv[8 + j];
  #pragma unroll
  for (int j = 0; j < 8; ++j) r[j] = r[j] + vv[16 + j];
  float s = ((r[0] + r[1]) + (r[2] + r[3])) + ((r[4] + r[5]) + (r[6] + r[7]));
  s = s + vv[24]; s = s + vv[25]; s = s + vv[26]; s = s + vv[27];

  float bestd = 1e30f; int bestk = 0x7fffffff;
  for (int t = 0; t < 8; ++t) {
    int k = t * 64 + lane;
    float dot = 0.f;
    #pragma unroll
    for (int j = 0; j < 28; ++j) dot = __builtin_fmaf(v[j], E1s[j * NCODE + k], dot);
    float d = (s - 2.0f * dot) + Ts[k];
    if (d < bestd || (d == bestd && k < bestk)) { bestd = d; bestk = k; }
  }
  for (int off = 32; off; off >>= 1) {
    float d2 = __shfl_down(bestd, off, 64);
    int   k2 = __shfl_down(bestk, off, 64);
    if (d2 < bestd || (d2 == bestd && k2 < bestk)) { bestd = d2; bestk = k2; }
  }
  int kstar = __shfl(bestk, 0, 64);
  float sq = 0.f;
  if (lane < 28) {
    int om = lane & 3, im = lane >> 2;
    float q = E1s[lane * NCODE + kstar];
    qW1[(size_t)(og * 4 + om) * KP + ig * 7 + im] = (f16)q;
    float dd = q - v[lane]; sq = dd * dd;
  }
  for (int off = 32; off; off >>= 1) sq += __shfl_down(sq, off, 64);
  if (lane == 0) atomicAdd(&diffacc[bid & 127], sq);
}

// ---------------- VQ W2: blocks (og<512, ig<32), dim 16 contiguous ----------------
__global__ void k_vq2(const float* __restrict__ W2, const float* __restrict__ E2,
                      f16* __restrict__ qW2, float* __restrict__ diffacc) {
  #pragma clang fp contract(off)
  __shared__ float E2s[16 * NCODE];
  __shared__ float Ts[NCODE];
  for (int i = threadIdx.x; i < 16 * NCODE; i += 256) E2s[i] = E2[i];
  __syncthreads();
  for (int k = threadIdx.x; k < NCODE; k += 256) {
    float e0 = E2s[k];
    float t = e0 * e0;
    for (int j = 1; j < 16; ++j) {
      float e = E2s[j * NCODE + k];
      float ee = e * e;
      t = t + ee;
    }
    Ts[k] = t;
  }
  __syncthreads();
  const int wid = threadIdx.x >> 6, lane = threadIdx.x & 63;
  const int bid = blockIdx.x * 4 + wid;          // < 16384
  const int og = bid >> 5, ig = bid & 31;
  float v[16], vv[16];
  #pragma unroll
  for (int j = 0; j < 16; ++j) {
    v[j] = W2[og * HDIM + ig * 16 + j];
    vv[j] = v[j] * v[j];
  }
  // numpy pairwise_sum, scalar path, n=16: r[j]=a[j]+a[8+j]; combine; no tail
  float r[8];
  #pragma unroll
  for (int j = 0; j < 8; ++j) r[j] = vv[j];
  #pragma unroll
  for (int j = 0; j < 8; ++j) r[j] = r[j] + vv[8 + j];
  float s = ((r[0] + r[1]) + (r[2] + r[3])) + ((r[4] + r[5]) + (r[6] + r[7]));

  float bestd = 1e30f; int bestk = 0x7fffffff;
  for (int t = 0; t < 8; ++t) {
    int k = t * 64 + lane;
    float dot = 0.f;
    #pragma unroll
    for (int j = 0; j < 16; ++j) dot = __builtin_fmaf(v[j], E2s[j * NCODE + k], dot);
    float d = (s - 2.0f * dot) + Ts[k];
    if (d < bestd || (d == bestd && k < bestk)) { bestd = d; bestk = k; }
  }
  for (int off = 32; off; off >>= 1) {
    float d2 = __shfl_down(bestd, off, 64);
    int   k2 = __shfl_down(bestk, off, 64);
    if (d2 < bestd || (d2 == bestd && k2 < bestk)) { bestd = d2; bestk = k2; }
  }
  int kstar = __shfl(bestk, 0, 64);
  float sq = 0.f;
  if (lane < 16) {
    float q = E2s[lane * NCODE + kstar];
    qW2[(size_t)og * HDIM + ig * 16 + lane] = (f16)q;
    float dd = q - v[lane]; sq = dd * dd;
  }
  for (int off = 32; off; off >>= 1) sq += __shfl_down(sq, off, 64);
  if (lane == 0) atomicAdd(&diffacc[bid & 127], sq);
}

// ---------------- C = relu(A @ Bw^T + bias), f16 in/out, fp32 accum ----------------
// A: (65536, lda) f16, Bw: (512, ldb) f16, C: (65536, 512) f16. N fixed 512 -> 4 col tiles.
__global__ void k_gemm(const f16* __restrict__ A, const f16* __restrict__ Bw,
                       const float* __restrict__ bias, f16* __restrict__ C,
                       int K, int lda, int ldb) {
  __shared__ __align__(16) f16 As[128 * 32];
  __shared__ __align__(16) f16 Bs[128 * 32];
  const int tid = threadIdx.x;
  const int bn = blockIdx.x & 3;
  const int bm = blockIdx.x >> 2;
  const int lane = tid & 63, wid = tid >> 6;
  const int waveM = wid & 1, waveN = wid >> 1;
  const int l15 = lane & 15, quad = lane >> 4;

  // staging chunks: c in [0,512), row = c>>2, 16B col chunk = (c&3)*8 f16
  const int c0 = tid, c1 = tid + 256;
  const f16* gA0 = A + (size_t)(bm * 128 + (c0 >> 2)) * lda + (c0 & 3) * 8;
  const f16* gA1 = A + (size_t)(bm * 128 + (c1 >> 2)) * lda + (c1 & 3) * 8;
  const f16* gB0 = Bw + (size_t)(bn * 128 + (c0 >> 2)) * ldb + (c0 & 3) * 8;
  const f16* gB1 = Bw + (size_t)(bn * 128 + (c1 >> 2)) * ldb + (c1 & 3) * 8;
  f16* lA0 = As + c0 * 8; f16* lA1 = As + c1 * 8;
  f16* lB0 = Bs + c0 * 8; f16* lB1 = Bs + c1 * 8;

  f32x4 acc[4][4];
  #pragma unroll
  for (int i = 0; i < 4; ++i)
    #pragma unroll
    for (int j = 0; j < 4; ++j) acc[i][j] = (f32x4){0.f, 0.f, 0.f, 0.f};

  const int aoff = (waveM * 64 + l15) * 32 + quad * 8;
  const int boff = (waveN * 64 + l15) * 32 + quad * 8;

  for (int k0 = 0; k0 < K; k0 += 32) {
    gld_lds16(gA0 + k0, lA0);
    gld_lds16(gA1 + k0, lA1);
    gld_lds16(gB0 + k0, lB0);
    gld_lds16(gB1 + k0, lB1);
    __syncthreads();
    f16x8 af[4], bf[4];
    #pragma unroll
    for (int i = 0; i < 4; ++i) af[i] = *(const f16x8*)(As + aoff + i * 16 * 32);
    #pragma unroll
    for (int j = 0; j < 4; ++j) bf[j] = *(const f16x8*)(Bs + boff + j * 16 * 32);
    #pragma unroll
    for (int i = 0; i < 4; ++i)
      #pragma unroll
      for (int j = 0; j < 4; ++j)
        acc[i][j] = __builtin_amdgcn_mfma_f32_16x16x32_f16(af[i], bf[j], acc[i][j], 0, 0, 0);
    __syncthreads();
  }
  // epilogue: C[row=quad*4+r][col=l15] per 16x16 tile (verified m89/m91 C/D mapping)
  const int colbase = bn * 128 + waveN * 64 + l15;
  float bcol[4];
  #pragma unroll
  for (int j = 0; j < 4; ++j) bcol[j] = bias[colbase + j * 16];
  const int rowbase = bm * 128 + waveM * 64 + quad * 4;
  #pragma unroll
  for (int i = 0; i < 4; ++i)
    #pragma unroll
    for (int r = 0; r < 4; ++r) {
      f16* crow = C + (size_t)(rowbase + i * 16 + r) * HDIM + colbase;
      #pragma unroll
      for (int j = 0; j < 4; ++j) {
        float v = acc[i][j][r] + bcol[j];
        crow[j * 16] = (f16)(v > 0.f ? v : 0.f);
      }
    }
}

// ---------------- per-column sum / sumsq of h (post-relu) ----------------
__global__ void k_stats(const f16* __restrict__ h, float* __restrict__ acc) {
  const int c = threadIdx.x;                        // 512 threads
  size_t base = (size_t)blockIdx.x * 128 * HDIM + c;
  float s = 0.f, s2 = 0.f;
  for (int i = 0; i < 128; ++i) {
    float v = (float)h[base + (size_t)i * HDIM];
    s += v; s2 += v * v;
  }
  atomicAdd(&acc[256 + c], s);
  atomicAdd(&acc[768 + c], s2);
}

// ---------------- BN coefficients + diff output + W3 f16 (padded 10->16 rows) ----------------
__global__ void k_bnprep(const float* __restrict__ acc, const float* __restrict__ gamma,
                         const float* __restrict__ beta, float* __restrict__ ab,
                         const float* __restrict__ W3, f16* __restrict__ W3h,
                         float* __restrict__ diff_out) {
  const int c = threadIdx.x;                        // 512 threads
  const float inv = 1.f / 65536.f;
  float mu = acc[256 + c] * inv;
  float msq = acc[768 + c] * inv;
  float var = msq - mu * mu;
  float a = gamma[c] / sqrtf(var + 1e-5f);
  ab[c] = a;
  ab[512 + c] = beta[c] - mu * a;
  #pragma unroll
  for (int o = 0; o < 16; ++o)
    W3h[o * HDIM + c] = (o < D_OUT) ? (f16)W3[o * HDIM + c] : (f16)0.f;
  if (c == 0) {
    float s1 = 0.f, s2 = 0.f;
    for (int i = 0; i < 128; ++i) { s1 += acc[i]; s2 += acc[128 + i]; }
    diff_out[0] = s1 * (1.f / 401408.f) + s2 * (1.f / 262144.f);
  }
}

// ---------------- hn = h*a[c] + b[c], in place ----------------
__global__ void k_bnapply(f16* __restrict__ h, const float* __restrict__ ab) {
  size_t t = (size_t)blockIdx.x * 256 + threadIdx.x;  // 4,194,304 threads
  int cg = (int)(t & 63) * 8;
  f16x8 v = *(f16x8*)(h + t * 8);
  #pragma unroll
  for (int j = 0; j < 8; ++j) {
    float f = (float)v[j] * ab[cg + j] + ab[512 + cg + j];
    v[j] = (f16)f;
  }
  *(f16x8*)(h + t * 8) = v;
}

// ---------------- out = h2 @ W3^T + b3, one wave per 16 rows, N padded to 16 ----------------
__global__ void k_final(const f16* __restrict__ h2, const f16* __restrict__ W3h,
                        const float* __restrict__ b3, float* __restrict__ out) {
  const int tid = threadIdx.x;
  const int wid = tid >> 6, lane = tid & 63;
  const int l15 = lane & 15, quad = lane >> 4;
  const int r0 = (blockIdx.x * 4 + wid) * 16;
  f32x4 acc = (f32x4){0.f, 0.f, 0.f, 0.f};
  const f16* arow = h2 + (size_t)(r0 + l15) * HDIM + quad * 8;
  const f16* brow = W3h + (size_t)l15 * HDIM + quad * 8;
  #pragma unroll
  for (int k0 = 0; k0 < HDIM; k0 += 32) {
    f16x8 a = *(const f16x8*)(arow + k0);
    f16x8 b = *(const f16x8*)(brow + k0);
    acc = __builtin_amdgcn_mfma_f32_16x16x32_f16(a, b, acc, 0, 0, 0);
  }
  if (l15 < D_OUT) {
    float bias = b3[l15];
    #pragma unroll
    for (int r = 0; r < 4; ++r)
      out[(size_t)(r0 + quad * 4 + r) * D_OUT + l15] = acc[r] + bias;
  }
}

extern "C" void kernel_launch(void* const* d_in, const int* in_sizes, int n_in,
                              void* d_out, int out_size, void* d_ws, size_t ws_size,
                              hipStream_t stream) {
  const float* x     = (const float*)d_in[0];
  const float* W1    = (const float*)d_in[1];
  const float* b1    = (const float*)d_in[2];
  const float* gamma = (const float*)d_in[3];
  const float* beta  = (const float*)d_in[4];
  const float* E1    = (const float*)d_in[5];
  const float* W2    = (const float*)d_in[6];
  const float* b2    = (const float*)d_in[7];
  const float* E2    = (const float*)d_in[8];
  const float* W3    = (const float*)d_in[9];
  const float* b3    = (const float*)d_in[10];
  float* out = (float*)d_out;

  char* ws = (char*)d_ws;
  // layout (all offsets 256B-aligned):
  float* accum = (float*)ws;                       //   5120 B used: [0,128) diff1, [128,256) diff2, [256,768) colsum, [768,1280) colsumsq
  f16* qW1h = (f16*)(ws + 8192);                   // 512*800*2 = 819200
  f16* qW2h = (f16*)(ws + 827392);                 // 512*512*2 = 524288
  f16* W3h  = (f16*)(ws + 1351680);                // 16*512*2  = 16384
  float* ab = (float*)(ws + 1368064);              // 1024*4    = 4096
  f16* xh   = (f16*)(ws + 1372160);                // 65536*800*2 = 104857600
  f16* h    = (f16*)(ws + 106229760);              // 65536*512*2 = 67108864  (total ~165 MB)
  f16* h2   = xh;                                  // xh dead after gemm1 -> reuse for h2

  hipMemsetAsync(ws, 0, 827392, stream);           // accum slots + qW1h (zero K-padding)
  k_convert_x<<<25600, 256, 0, stream>>>(x, xh);
  k_vq1<<<3584, 256, 0, stream>>>(W1, E1, qW1h, accum);
  k_vq2<<<4096, 256, 0, stream>>>(W2, E2, qW2h, accum + 128);
  k_gemm<<<2048, 256, 0, stream>>>(xh, qW1h, b1, h, KP, KP, KP);
  k_stats<<<512, 512, 0, stream>>>(h, accum);
  k_bnprep<<<1, 512, 0, stream>>>(accum, gamma, beta, ab, W3, W3h, out + (size_t)BATCH * D_OUT);
  k_bnapply<<<16384, 256, 0, stream>>>(h, ab);
  k_gemm<<<2048, 256, 0, stream>>>(h, qW2h, b2, h2, HDIM, HDIM, HDIM);
  k_final<<<1024, 256, 0, stream>>>(h2, W3h, b3, out);
}

// Round 5
// 601.758 us; speedup vs baseline: 1.0484x; 1.0484x over previous
//
#include <hip/hip_runtime.h>
#include <stdint.h>

// Sizes (fixed by the problem)
#define BATCH   65536
#define D_IN    784
#define KP      800      // D_IN padded to a multiple of BK=32
#define HDIM    512
#define D_OUT   10
#define NCODE   512
#define HT_LD   136      // epilogue LDS tile leading dim (128 + 8 f16 pad)

typedef _Float16 f16;
typedef _Float16 f16x8 __attribute__((ext_vector_type(8)));
typedef float    f32x4 __attribute__((ext_vector_type(4)));

__device__ __forceinline__ void gld_lds16(const void* g, void* l) {
  __builtin_amdgcn_global_load_lds((const __attribute__((address_space(1))) void*)g,
                                   (__attribute__((address_space(3))) void*)l, 16, 0, 0);
}

// ---------------- x: fp32 (65536,784) -> f16 (65536,800) zero-padded ----------------
__global__ void k_convert_x(const float* __restrict__ x, f16* __restrict__ xh) {
  int t = blockIdx.x * 256 + threadIdx.x;        // 65536*100 threads
  int r = t / 100;
  int c = (t - r * 100) * 8;
  f16x8 o;
  if (c < D_IN) {  // 784 % 8 == 0, so chunks are fully valid or fully pad
    const float4 a = *(const float4*)(x + (size_t)r * D_IN + c);
    const float4 b = *(const float4*)(x + (size_t)r * D_IN + c + 4);
    o[0]=(f16)a.x; o[1]=(f16)a.y; o[2]=(f16)a.z; o[3]=(f16)a.w;
    o[4]=(f16)b.x; o[5]=(f16)b.y; o[6]=(f16)b.z; o[7]=(f16)b.w;
  } else {
    #pragma unroll
    for (int j = 0; j < 8; ++j) o[j] = (f16)0.f;
  }
  *(f16x8*)(xh + (size_t)r * KP + c) = o;
}

// ---------------- VQ W1: blocks (og<128, ig<112), dim 28 ----------------
// Replicates numpy-fp32 semantics (verified R3: absmax 454 -> 0.0156):
//   dist = fl(fl(s - 2*dot) + t); s = numpy pairwise scalar 8-acc; dot =
//   ascending-k fp32 FMA chain; t = sequential axis-0 sum; first-min argmin.
__global__ void k_vq1(const float* __restrict__ W1, const float* __restrict__ E1,
                      f16* __restrict__ qW1, float* __restrict__ diffacc) {
  #pragma clang fp contract(off)
  __shared__ float E1s[28 * NCODE];
  __shared__ float Ts[NCODE];
  for (int i = threadIdx.x; i < 28 * NCODE; i += 256) E1s[i] = E1[i];
  __syncthreads();
  for (int k = threadIdx.x; k < NCODE; k += 256) {
    float e0 = E1s[k];
    float t = e0 * e0;
    for (int j = 1; j < 28; ++j) {
      float e = E1s[j * NCODE + k];
      float ee = e * e;
      t = t + ee;
    }
    Ts[k] = t;
  }
  __syncthreads();
  const int wid = threadIdx.x >> 6, lane = threadIdx.x & 63;
  const int bid = blockIdx.x * 4 + wid;          // < 14336
  const int og = bid / 112, ig = bid % 112;
  float v[28], vv[28];
  #pragma unroll
  for (int j = 0; j < 28; ++j) {
    int om = j & 3, im = j >> 2;
    v[j] = W1[(og * 4 + om) * D_IN + ig * 7 + im];
    vv[j] = v[j] * v[j];
  }
  float r[8];
  #pragma unroll
  for (int j = 0; j < 8; ++j) r[j] = vv[j];
  #pragma unroll
  for (int j = 0; j < 8; ++j) r[j] = r[j] + vv[8 + j];
  #pragma unroll
  for (int j = 0; j < 8; ++j) r[j] = r[j] + vv[16 + j];
  float s = ((r[0] + r[1]) + (r[2] + r[3])) + ((r[4] + r[5]) + (r[6] + r[7]));
  s = s + vv[24]; s = s + vv[25]; s = s + vv[26]; s = s + vv[27];

  float bestd = 1e30f; int bestk = 0x7fffffff;
  for (int t = 0; t < 8; ++t) {
    int k = t * 64 + lane;
    float dot = 0.f;
    #pragma unroll
    for (int j = 0; j < 28; ++j) dot = __builtin_fmaf(v[j], E1s[j * NCODE + k], dot);
    float d = (s - 2.0f * dot) + Ts[k];
    if (d < bestd || (d == bestd && k < bestk)) { bestd = d; bestk = k; }
  }
  for (int off = 32; off; off >>= 1) {
    float d2 = __shfl_down(bestd, off, 64);
    int   k2 = __shfl_down(bestk, off, 64);
    if (d2 < bestd || (d2 == bestd && k2 < bestk)) { bestd = d2; bestk = k2; }
  }
  int kstar = __shfl(bestk, 0, 64);
  float sq = 0.f;
  if (lane < 28) {
    int om = lane & 3, im = lane >> 2;
    float q = E1s[lane * NCODE + kstar];
    qW1[(size_t)(og * 4 + om) * KP + ig * 7 + im] = (f16)q;
    float dd = q - v[lane]; sq = dd * dd;
  }
  for (int off = 32; off; off >>= 1) sq += __shfl_down(sq, off, 64);
  if (lane == 0) atomicAdd(&diffacc[bid & 127], sq);
}

// ---------------- VQ W2: blocks (og<512, ig<32), dim 16 contiguous ----------------
__global__ void k_vq2(const float* __restrict__ W2, const float* __restrict__ E2,
                      f16* __restrict__ qW2, float* __restrict__ diffacc) {
  #pragma clang fp contract(off)
  __shared__ float E2s[16 * NCODE];
  __shared__ float Ts[NCODE];
  for (int i = threadIdx.x; i < 16 * NCODE; i += 256) E2s[i] = E2[i];
  __syncthreads();
  for (int k = threadIdx.x; k < NCODE; k += 256) {
    float e0 = E2s[k];
    float t = e0 * e0;
    for (int j = 1; j < 16; ++j) {
      float e = E2s[j * NCODE + k];
      float ee = e * e;
      t = t + ee;
    }
    Ts[k] = t;
  }
  __syncthreads();
  const int wid = threadIdx.x >> 6, lane = threadIdx.x & 63;
  const int bid = blockIdx.x * 4 + wid;          // < 16384
  const int og = bid >> 5, ig = bid & 31;
  float v[16], vv[16];
  #pragma unroll
  for (int j = 0; j < 16; ++j) {
    v[j] = W2[og * HDIM + ig * 16 + j];
    vv[j] = v[j] * v[j];
  }
  float r[8];
  #pragma unroll
  for (int j = 0; j < 8; ++j) r[j] = vv[j];
  #pragma unroll
  for (int j = 0; j < 8; ++j) r[j] = r[j] + vv[8 + j];
  float s = ((r[0] + r[1]) + (r[2] + r[3])) + ((r[4] + r[5]) + (r[6] + r[7]));

  float bestd = 1e30f; int bestk = 0x7fffffff;
  for (int t = 0; t < 8; ++t) {
    int k = t * 64 + lane;
    float dot = 0.f;
    #pragma unroll
    for (int j = 0; j < 16; ++j) dot = __builtin_fmaf(v[j], E2s[j * NCODE + k], dot);
    float d = (s - 2.0f * dot) + Ts[k];
    if (d < bestd || (d == bestd && k < bestk)) { bestd = d; bestk = k; }
  }
  for (int off = 32; off; off >>= 1) {
    float d2 = __shfl_down(bestd, off, 64);
    int   k2 = __shfl_down(bestk, off, 64);
    if (d2 < bestd || (d2 == bestd && k2 < bestk)) { bestd = d2; bestk = k2; }
  }
  int kstar = __shfl(bestk, 0, 64);
  float sq = 0.f;
  if (lane < 16) {
    float q = E2s[lane * NCODE + kstar];
    qW2[(size_t)og * HDIM + ig * 16 + lane] = (f16)q;
    float dd = q - v[lane]; sq = dd * dd;
  }
  for (int off = 32; off; off >>= 1) sq += __shfl_down(sq, off, 64);
  if (lane == 0) atomicAdd(&diffacc[bid & 127], sq);
}

// ---------------- GEMM1: h = relu(xh @ qW1^T + b1), fused column stats ----------------
// h coalesced via LDS repack; stats (sum, sumsq of fp32 pre-round values) -> atomics.
__global__ void k_gemm1(const f16* __restrict__ A, const f16* __restrict__ Bw,
                        const float* __restrict__ bias, f16* __restrict__ C,
                        float* __restrict__ statacc) {
  __shared__ __align__(16) char lds_all[HT_LD * 128 * 2];   // 34816 B union
  __shared__ float cls[128], cls2[128];
  f16* As = (f16*)lds_all;
  f16* Bs = (f16*)(lds_all + 8192);
  f16* ht = (f16*)lds_all;
  const int tid = threadIdx.x;
  const int bn = blockIdx.x & 3;
  const int bm = blockIdx.x >> 2;
  const int lane = tid & 63, wid = tid >> 6;
  const int waveM = wid & 1, waveN = wid >> 1;
  const int l15 = lane & 15, quad = lane >> 4;

  if (tid < 128) cls[tid] = 0.f; else cls2[tid - 128] = 0.f;

  const int c0 = tid, c1 = tid + 256;
  const f16* gA0 = A + (size_t)(bm * 128 + (c0 >> 2)) * KP + (c0 & 3) * 8;
  const f16* gA1 = A + (size_t)(bm * 128 + (c1 >> 2)) * KP + (c1 & 3) * 8;
  const f16* gB0 = Bw + (size_t)(bn * 128 + (c0 >> 2)) * KP + (c0 & 3) * 8;
  const f16* gB1 = Bw + (size_t)(bn * 128 + (c1 >> 2)) * KP + (c1 & 3) * 8;
  f16* lA0 = As + c0 * 8; f16* lA1 = As + c1 * 8;
  f16* lB0 = Bs + c0 * 8; f16* lB1 = Bs + c1 * 8;

  f32x4 acc[4][4];
  #pragma unroll
  for (int i = 0; i < 4; ++i)
    #pragma unroll
    for (int j = 0; j < 4; ++j) acc[i][j] = (f32x4){0.f, 0.f, 0.f, 0.f};

  const int aoff = (waveM * 64 + l15) * 32 + quad * 8;
  const int boff = (waveN * 64 + l15) * 32 + quad * 8;

  for (int k0 = 0; k0 < KP; k0 += 32) {
    gld_lds16(gA0 + k0, lA0);
    gld_lds16(gA1 + k0, lA1);
    gld_lds16(gB0 + k0, lB0);
    gld_lds16(gB1 + k0, lB1);
    __syncthreads();
    f16x8 af[4], bf[4];
    #pragma unroll
    for (int i = 0; i < 4; ++i) af[i] = *(const f16x8*)(As + aoff + i * 16 * 32);
    #pragma unroll
    for (int j = 0; j < 4; ++j) bf[j] = *(const f16x8*)(Bs + boff + j * 16 * 32);
    #pragma unroll
    for (int i = 0; i < 4; ++i)
      #pragma unroll
      for (int j = 0; j < 4; ++j)
        acc[i][j] = __builtin_amdgcn_mfma_f32_16x16x32_f16(af[i], bf[j], acc[i][j], 0, 0, 0);
    __syncthreads();
  }
  // epilogue: relu+bias -> LDS tile (f16) + per-column stats on fp32 values
  const int colbase = bn * 128 + waveN * 64 + l15;
  float bcol[4];
  #pragma unroll
  for (int j = 0; j < 4; ++j) bcol[j] = bias[colbase + j * 16];
  float cs[4] = {0.f,0.f,0.f,0.f}, cs2[4] = {0.f,0.f,0.f,0.f};
  #pragma unroll
  for (int i = 0; i < 4; ++i)
    #pragma unroll
    for (int r2 = 0; r2 < 4; ++r2) {
      int rloc = waveM * 64 + quad * 4 + i * 16 + r2;
      #pragma unroll
      for (int j = 0; j < 4; ++j) {
        float v = acc[i][j][r2] + bcol[j];
        v = v > 0.f ? v : 0.f;
        ht[rloc * HT_LD + waveN * 64 + j * 16 + l15] = (f16)v;
        cs[j] += v; cs2[j] += v * v;
      }
    }
  // reduce over quads (same column), then LDS atomics by quad==0 lanes
  #pragma unroll
  for (int j = 0; j < 4; ++j) {
    cs[j]  += __shfl_xor(cs[j], 16, 64);  cs[j]  += __shfl_xor(cs[j], 32, 64);
    cs2[j] += __shfl_xor(cs2[j], 16, 64); cs2[j] += __shfl_xor(cs2[j], 32, 64);
  }
  if (quad == 0) {
    #pragma unroll
    for (int j = 0; j < 4; ++j) {
      atomicAdd(&cls[waveN * 64 + j * 16 + l15], cs[j]);
      atomicAdd(&cls2[waveN * 64 + j * 16 + l15], cs2[j]);
    }
  }
  __syncthreads();
  if (tid < 128) atomicAdd(&statacc[256 + bn * 128 + tid], cls[tid]);
  else           atomicAdd(&statacc[768 + bn * 128 + (tid - 128)], cls2[tid - 128]);
  // coalesced h write-back: thread t -> row t>>1, 64-col half t&1
  {
    const int rloc = tid >> 1, half = tid & 1;
    f16* crow = C + (size_t)(bm * 128 + rloc) * HDIM + bn * 128 + half * 64;
    const f16* srow = ht + rloc * HT_LD + half * 64;
    #pragma unroll
    for (int j = 0; j < 8; ++j)
      *(f16x8*)(crow + j * 8) = *(const f16x8*)(srow + j * 8);
  }
}

// ---------------- BN coefficients + diff output + W3 f16 (padded 10->16 rows) ----------------
__global__ void k_bnprep(const float* __restrict__ acc, const float* __restrict__ gamma,
                         const float* __restrict__ beta, float* __restrict__ ab,
                         const float* __restrict__ W3, f16* __restrict__ W3h,
                         float* __restrict__ diff_out) {
  const int c = threadIdx.x;                        // 512 threads
  const float inv = 1.f / 65536.f;
  float mu = acc[256 + c] * inv;
  float msq = acc[768 + c] * inv;
  float var = msq - mu * mu;
  float a = gamma[c] / sqrtf(var + 1e-5f);
  ab[c] = a;
  ab[512 + c] = beta[c] - mu * a;
  #pragma unroll
  for (int o = 0; o < 16; ++o)
    W3h[o * HDIM + c] = (o < D_OUT) ? (f16)W3[o * HDIM + c] : (f16)0.f;
  if (c == 0) {
    float s1 = 0.f, s2 = 0.f;
    for (int i = 0; i < 128; ++i) { s1 += acc[i]; s2 += acc[128 + i]; }
    diff_out[0] = s1 * (1.f / 401408.f) + s2 * (1.f / 262144.f);
  }
}

// ---------------- fold BN into qW2 (in place) + bias2 ----------------
// bn(h)@qW2^T = h@(a.*qW2)^T + [b2 + sum_k b[k]*qW2[:,k]]
__global__ void k_bnfold(f16* __restrict__ qW2, const float* __restrict__ ab,
                         const float* __restrict__ b2, float* __restrict__ bias2) {
  __shared__ float red[256];
  const int n = blockIdx.x, t = threadIdx.x;        // 512 blocks x 256 threads
  float partial = 0.f;
  #pragma unroll
  for (int kk = 0; kk < 2; ++kk) {
    int k = t + kk * 256;
    float w = (float)qW2[n * HDIM + k];
    partial += ab[512 + k] * w;
    qW2[n * HDIM + k] = (f16)(ab[k] * w);
  }
  red[t] = partial; __syncthreads();
  for (int s = 128; s > 0; s >>= 1) { if (t < s) red[t] += red[t + s]; __syncthreads(); }
  if (t == 0) bias2[n] = b2[n] + red[0];
}

// ---------------- GEMM2 + fused final layer ----------------
// h2tile = relu(h @ qW2s^T + bias2) -> LDS; out += h2tile @ W3h[:, bn*128..]^T (+b3 once, bn==0)
__global__ void k_gemm2f(const f16* __restrict__ A, const f16* __restrict__ Bw,
                         const float* __restrict__ bias2, const f16* __restrict__ W3h,
                         const float* __restrict__ b3, float* __restrict__ out) {
  __shared__ __align__(16) char lds_all[HT_LD * 128 * 2];   // 34816 B union
  f16* As = (f16*)lds_all;
  f16* Bs = (f16*)(lds_all + 8192);
  f16* ht = (f16*)lds_all;
  const int tid = threadIdx.x;
  const int bn = blockIdx.x & 3;
  const int bm = blockIdx.x >> 2;
  const int lane = tid & 63, wid = tid >> 6;
  const int waveM = wid & 1, waveN = wid >> 1;
  const int l15 = lane & 15, quad = lane >> 4;

  const int c0 = tid, c1 = tid + 256;
  const f16* gA0 = A + (size_t)(bm * 128 + (c0 >> 2)) * HDIM + (c0 & 3) * 8;
  const f16* gA1 = A + (size_t)(bm * 128 + (c1 >> 2)) * HDIM + (c1 & 3) * 8;
  const f16* gB0 = Bw + (size_t)(bn * 128 + (c0 >> 2)) * HDIM + (c0 & 3) * 8;
  const f16* gB1 = Bw + (size_t)(bn * 128 + (c1 >> 2)) * HDIM + (c1 & 3) * 8;
  f16* lA0 = As + c0 * 8; f16* lA1 = As + c1 * 8;
  f16* lB0 = Bs + c0 * 8; f16* lB1 = Bs + c1 * 8;

  f32x4 acc[4][4];
  #pragma unroll
  for (int i = 0; i < 4; ++i)
    #pragma unroll
    for (int j = 0; j < 4; ++j) acc[i][j] = (f32x4){0.f, 0.f, 0.f, 0.f};

  const int aoff = (waveM * 64 + l15) * 32 + quad * 8;
  const int boff = (waveN * 64 + l15) * 32 + quad * 8;

  for (int k0 = 0; k0 < HDIM; k0 += 32) {
    gld_lds16(gA0 + k0, lA0);
    gld_lds16(gA1 + k0, lA1);
    gld_lds16(gB0 + k0, lB0);
    gld_lds16(gB1 + k0, lB1);
    __syncthreads();
    f16x8 af[4], bf[4];
    #pragma unroll
    for (int i = 0; i < 4; ++i) af[i] = *(const f16x8*)(As + aoff + i * 16 * 32);
    #pragma unroll
    for (int j = 0; j < 4; ++j) bf[j] = *(const f16x8*)(Bs + boff + j * 16 * 32);
    #pragma unroll
    for (int i = 0; i < 4; ++i)
      #pragma unroll
      for (int j = 0; j < 4; ++j)
        acc[i][j] = __builtin_amdgcn_mfma_f32_16x16x32_f16(af[i], bf[j], acc[i][j], 0, 0, 0);
    __syncthreads();
  }
  // epilogue: relu+bias2 -> LDS f16 tile (no global h2)
  const int colbase = bn * 128 + waveN * 64 + l15;
  float bcol[4];
  #pragma unroll
  for (int j = 0; j < 4; ++j) bcol[j] = bias2[colbase + j * 16];
  #pragma unroll
  for (int i = 0; i < 4; ++i)
    #pragma unroll
    for (int r2 = 0; r2 < 4; ++r2) {
      int rloc = waveM * 64 + quad * 4 + i * 16 + r2;
      #pragma unroll
      for (int j = 0; j < 4; ++j) {
        float v = acc[i][j][r2] + bcol[j];
        v = v > 0.f ? v : 0.f;
        ht[rloc * HT_LD + waveN * 64 + j * 16 + l15] = (f16)v;
      }
    }
  __syncthreads();
  // final layer: rows [wid*32, wid*32+32), N=16 (W3h padded), K=128 = this tile's
  // columns bn*128..bn*128+127 -> W3h columns MUST be offset by bn*128 (R4 bug).
  f32x4 oacc[2];
  oacc[0] = (f32x4){0.f,0.f,0.f,0.f}; oacc[1] = (f32x4){0.f,0.f,0.f,0.f};
  #pragma unroll
  for (int ks = 0; ks < 4; ++ks) {
    f16x8 bfr = *(const f16x8*)(W3h + l15 * HDIM + bn * 128 + ks * 32 + quad * 8);
    #pragma unroll
    for (int i2 = 0; i2 < 2; ++i2) {
      f16x8 afr = *(const f16x8*)(ht + (wid * 32 + i2 * 16 + l15) * HT_LD + ks * 32 + quad * 8);
      oacc[i2] = __builtin_amdgcn_mfma_f32_16x16x32_f16(afr, bfr, oacc[i2], 0, 0, 0);
    }
  }
  if (l15 < D_OUT) {
    float badd = (bn == 0) ? b3[l15] : 0.f;
    #pragma unroll
    for (int i2 = 0; i2 < 2; ++i2)
      #pragma unroll
      for (int r2 = 0; r2 < 4; ++r2) {
        int row = bm * 128 + wid * 32 + i2 * 16 + quad * 4 + r2;
        atomicAdd(&out[(size_t)row * D_OUT + l15], oacc[i2][r2] + badd);
      }
  }
}

extern "C" void kernel_launch(void* const* d_in, const int* in_sizes, int n_in,
                              void* d_out, int out_size, void* d_ws, size_t ws_size,
                              hipStream_t stream) {
  const float* x     = (const float*)d_in[0];
  const float* W1    = (const float*)d_in[1];
  const float* b1    = (const float*)d_in[2];
  const float* gamma = (const float*)d_in[3];
  const float* beta  = (const float*)d_in[4];
  const float* E1    = (const float*)d_in[5];
  const float* W2    = (const float*)d_in[6];
  const float* b2    = (const float*)d_in[7];
  const float* E2    = (const float*)d_in[8];
  const float* W3    = (const float*)d_in[9];
  const float* b3    = (const float*)d_in[10];
  float* out = (float*)d_out;

  char* ws = (char*)d_ws;
  float* accum = (float*)ws;                       // [0,128) diff1, [128,256) diff2, [256,768) colsum, [768,1280) colsumsq
  f16* qW1h = (f16*)(ws + 8192);                   // 512*800*2 = 819200
  f16* qW2h = (f16*)(ws + 827392);                 // 512*512*2 = 524288
  f16* W3h  = (f16*)(ws + 1351680);                // 16*512*2  = 16384
  float* ab = (float*)(ws + 1368064);              // 1024*4
  float* bias2 = (float*)(ws + 1372160);           // 512*4
  f16* xh   = (f16*)(ws + 1376256);                // 65536*800*2 = 104857600
  f16* h    = (f16*)(ws + 106233856);              // 65536*512*2 = 67108864

  hipMemsetAsync(ws, 0, 827392, stream);           // accum + qW1h (zero K-padding)
  hipMemsetAsync(d_out, 0, (size_t)out_size * 4, stream);  // out accumulated via atomics
  k_convert_x<<<25600, 256, 0, stream>>>(x, xh);
  k_vq1<<<3584, 256, 0, stream>>>(W1, E1, qW1h, accum);
  k_vq2<<<4096, 256, 0, stream>>>(W2, E2, qW2h, accum + 128);
  k_gemm1<<<2048, 256, 0, stream>>>(xh, qW1h, b1, h, accum);
  k_bnprep<<<1, 512, 0, stream>>>(accum, gamma, beta, ab, W3, W3h, out + (size_t)BATCH * D_OUT);
  k_bnfold<<<512, 256, 0, stream>>>(qW2h, ab, b2, bias2);
  k_gemm2f<<<2048, 256, 0, stream>>>(h, qW2h, bias2, W3h, b3, out);
}